// Round 1
// baseline (71.396 us; speedup 1.0000x reference)
//
#include <hip/hip_runtime.h>
#include <cstddef>

#define NB   4
#define CIN  64
#define COUT 64
#define H    128
#define W    128
#define TAPS 9

#define PX   64          // pixels per block (one row segment)
#define CCH  16          // channel chunk
#define ROWS (CCH*TAPS)  // 144 corrected rows per chunk

// wT[ckl][o] = weight[o][ckl]   (ckl = c*9 + k*3 + l), 576 x 64
__global__ void transpose_weight(const float* __restrict__ w, float* __restrict__ wT) {
    int idx = blockIdx.x * blockDim.x + threadIdx.x;
    if (idx >= 576 * 64) return;
    int o = idx & 63;
    int ckl = idx >> 6;
    wT[idx] = w[o * 576 + ckl];
}

__launch_bounds__(256)
__global__ void pac_conv(const float* __restrict__ x, const float* __restrict__ Kp,
                         const float* __restrict__ wT, const float* __restrict__ bias,
                         float* __restrict__ out) {
    __shared__ float sK[TAPS][PX];
    __shared__ float sInvKsum[PX];
    __shared__ float sCor[ROWS][PX];   // 36864 B

    const int blk = blockIdx.x;               // NB*H*(W/PX) = 1024
    const int wseg = blk & ((W / PX) - 1);    // W/PX = 2
    const int h    = (blk / (W / PX)) & (H - 1);
    const int n    = blk / ((W / PX) * H);
    const int w0   = wseg * PX;

    const int t    = threadIdx.x;
    const int lane = t & 63;
    const int o0   = __builtin_amdgcn_readfirstlane((t >> 6) * 16);

    // stage adapting kernel K and 1/sum(K) per pixel
    for (int i = t; i < TAPS * PX; i += 256) {
        int tap = i >> 6, px = i & 63;
        sK[tap][px] = Kp[((n * TAPS + tap) * H + h) * W + w0 + px];
    }
    __syncthreads();
    if (t < PX) {
        float s = 0.f;
        #pragma unroll
        for (int tap = 0; tap < TAPS; ++tap) s += sK[tap][t];
        sInvKsum[t] = 1.0f / s;
    }

    float acc[16];
    #pragma unroll
    for (int j = 0; j < 16; ++j) acc[j] = 0.f;

    for (int cc = 0; cc < CIN; cc += CCH) {
        __syncthreads();   // protect sCor (and sK/sInvKsum on iter 0)

        // stage corrected[(c,k,l)][px] for this channel chunk
        for (int pair = t; pair < CCH * PX; pair += 256) {
            int cl = pair >> 6;
            int px = pair & 63;
            int c  = cc + cl;
            const float* xb = x + ((size_t)(n * CIN + c) * H) * W;

            float xv[TAPS];
            float s1 = 0.f;
            #pragma unroll
            for (int k = 0; k < 3; ++k) {
                int hh = h + k - 1;
                #pragma unroll
                for (int l = 0; l < 3; ++l) {
                    int ww = w0 + px + l - 1;
                    float v = 0.f;
                    if (hh >= 0 && hh < H && ww >= 0 && ww < W)
                        v = xb[hh * W + ww];
                    xv[k * 3 + l] = v;
                    s1 += v * sK[k * 3 + l][px];
                }
            }
            float dom = s1 * sInvKsum[px];
            #pragma unroll
            for (int tap = 0; tap < TAPS; ++tap) {
                float kv = sK[tap][px];
                sCor[cl * TAPS + tap][px] = kv * (xv[tap] - dom) + dom;
            }
        }
        __syncthreads();

        // GEMM: each wave owns 16 output channels, lanes = pixels
        const float* wTb = wT + (cc * TAPS) * 64 + o0;
        for (int r = 0; r < ROWS; ++r) {
            float cval = sCor[r][lane];
            const float* wr = wTb + r * 64;   // wave-uniform -> scalar loads
            #pragma unroll
            for (int j = 0; j < 16; ++j)
                acc[j] += wr[j] * cval;
        }
    }

    #pragma unroll
    for (int j = 0; j < 16; ++j) {
        int o = o0 + j;
        out[((size_t)(n * COUT + o) * H + h) * W + w0 + lane] = acc[j] + bias[o];
    }
}

extern "C" void kernel_launch(void* const* d_in, const int* in_sizes, int n_in,
                              void* d_out, int out_size, void* d_ws, size_t ws_size,
                              hipStream_t stream) {
    const float* x    = (const float*)d_in[0];
    const float* Kp   = (const float*)d_in[1];
    const float* wgt  = (const float*)d_in[2];
    const float* bias = (const float*)d_in[3];
    float* out = (float*)d_out;
    float* wT  = (float*)d_ws;   // 576*64 floats = 147456 B

    transpose_weight<<<(576 * 64 + 255) / 256, 256, 0, stream>>>(wgt, wT);

    dim3 grid(NB * H * (W / PX));   // 1024 blocks
    pac_conv<<<grid, 256, 0, stream>>>(x, Kp, wT, bias, out);
}

// Round 2
// 33.783 us; speedup vs baseline: 2.1134x; 2.1134x over previous
//
#include <hip/hip_runtime.h>
#include <cstddef>
#include <cstdint>

typedef __attribute__((ext_vector_type(8))) short bf16x8;
typedef __attribute__((ext_vector_type(4))) short short4v;
typedef __attribute__((ext_vector_type(4))) float f32x4;

#define NB 4
#define CIN 64
#define COUT 64
#define HH 128
#define WW 128
#define TAPS 9
#define PX 64
#define CCH 16
#define KCH 160      // padded K per chunk (144 real + 16 zero)
#define KTOT 640     // 4 chunks * 160
#define STR 164      // sCorT row stride in bf16 (328 B: 8B-aligned, gcd(82,32)=2 -> low conflicts)

__device__ __forceinline__ unsigned short f2bf(float f) {
    union { float f; unsigned u; } v; v.f = f;
    unsigned u = v.u + 0x7FFFu + ((v.u >> 16) & 1u);   // RNE
    return (unsigned short)(u >> 16);
}

// wB[o][kk], kk = chunk*160 + tap*16 + c_local, zero-padded at klocal 144..159
__global__ void prep_weight(const float* __restrict__ w, unsigned short* __restrict__ wB) {
    int idx = blockIdx.x * blockDim.x + threadIdx.x;
    if (idx >= COUT * KTOT) return;
    int o = idx / KTOT;
    int kk = idx - o * KTOT;
    int chunk = kk / KCH;
    int kl = kk - chunk * KCH;
    unsigned short v = 0;
    if (kl < CCH * TAPS) {
        int tap = kl >> 4;
        int cl = kl & 15;
        int c = chunk * CCH + cl;
        v = f2bf(w[(o * CIN + c) * TAPS + tap]);
    }
    wB[idx] = v;
}

__launch_bounds__(256)
__global__ void pac_conv(const float* __restrict__ x, const float* __restrict__ Kp,
                         const unsigned short* __restrict__ wB,
                         const float* __restrict__ bias, float* __restrict__ out) {
    __shared__ __align__(16) unsigned short sCorT[PX][STR];  // 20992 B, reused as f32 sOut[64][65]
    __shared__ float sK[TAPS][PX];
    __shared__ float sInv[PX];

    const int blk = blockIdx.x;            // 4*128*2 = 1024
    const int w0 = (blk & 1) * PX;
    const int h = (blk >> 1) & (HH - 1);
    const int n = blk >> 8;

    const int t = threadIdx.x;
    const int lane = t & 63;
    const int wv = t >> 6;                 // wave 0..3
    const int spx = lane;                  // staging pixel = lane

    // stage adapting kernel
    for (int i = t; i < TAPS * PX; i += 256) {
        int tap = i >> 6, px = i & 63;
        sK[tap][px] = Kp[((n * TAPS + tap) * HH + h) * WW + w0 + px];
    }
    // zero the K-pad rows (klocal 144..159) once; staging never touches them
    for (int i = t; i < PX * 16; i += 256) {
        sCorT[i >> 4][144 + (i & 15)] = 0;
    }
    __syncthreads();
    if (t < PX) {
        float s = 0.f;
        #pragma unroll
        for (int tap = 0; tap < TAPS; ++tap) s += sK[tap][t];
        sInv[t] = 1.0f / s;
    }
    __syncthreads();

    // hoist per-pixel adapting kernel into registers (px fixed per thread)
    float kreg[TAPS];
    #pragma unroll
    for (int tap = 0; tap < TAPS; ++tap) kreg[tap] = sK[tap][spx];
    const float inv = sInv[spx];

    f32x4 acc[4];
    #pragma unroll
    for (int i = 0; i < 4; ++i) acc[i] = (f32x4){0.f, 0.f, 0.f, 0.f};

    const int o0 = wv * 16;
    const int l15 = lane & 15;
    const int kg = (lane >> 4) * 8;

    for (int chunk = 0; chunk < 4; ++chunk) {
        __syncthreads();                   // protect sCorT vs previous MFMA reads
        const int cbase = chunk * CCH;
        #pragma unroll
        for (int it = 0; it < 4; ++it) {
            const int cl = wv + it * 4;    // 4 waves x 4 iters cover c_local 0..15
            const float* xb = x + (size_t)(n * CIN + cbase + cl) * (HH * WW);
            float xv[TAPS];
            float s1 = 0.f;
            #pragma unroll
            for (int k = 0; k < 3; ++k) {
                const int hh = h + k - 1;
                const bool hok = (unsigned)hh < (unsigned)HH;
                #pragma unroll
                for (int l = 0; l < 3; ++l) {
                    const int wc = w0 + spx + l - 1;
                    const bool ok = hok && ((unsigned)wc < (unsigned)WW);
                    float v = ok ? xb[hh * WW + wc] : 0.f;
                    xv[k * 3 + l] = v;
                    s1 = fmaf(v, kreg[k * 3 + l], s1);
                }
            }
            const float dom = s1 * inv;
            #pragma unroll
            for (int tap = 0; tap < TAPS; ++tap) {
                sCorT[spx][tap * 16 + cl] = f2bf(fmaf(kreg[tap], xv[tap] - dom, dom));
            }
        }
        __syncthreads();

        // MFMA: wave owns 16 outputs (N) x 64 px (M); A=cor[px][k], B=wB[o][k]
        const unsigned short* wrow = wB + (size_t)(o0 + l15) * KTOT + chunk * KCH + kg;
        #pragma unroll
        for (int step = 0; step < 5; ++step) {
            const int k0 = step * 32;
            bf16x8 bfrag = *reinterpret_cast<const bf16x8*>(wrow + k0);
            #pragma unroll
            for (int pt = 0; pt < 4; ++pt) {
                const unsigned short* ap = &sCorT[pt * 16 + l15][k0 + kg];
                short4v alo = *reinterpret_cast<const short4v*>(ap);
                short4v ahi = *reinterpret_cast<const short4v*>(ap + 4);
                bf16x8 afrag;
                #pragma unroll
                for (int j = 0; j < 4; ++j) { afrag[j] = alo[j]; afrag[4 + j] = ahi[j]; }
                acc[pt] = __builtin_amdgcn_mfma_f32_16x16x32_bf16(afrag, bfrag, acc[pt], 0, 0, 0);
            }
        }
    }

    // epilogue: transpose through LDS so stores are 256B coalesced
    __syncthreads();
    float* sOut = reinterpret_cast<float*>(&sCorT[0][0]);   // [64][65] f32 = 16640 B
    #pragma unroll
    for (int pt = 0; pt < 4; ++pt) {
        #pragma unroll
        for (int r = 0; r < 4; ++r) {
            const int px = pt * 16 + (lane >> 4) * 4 + r;   // D: row=M=px
            sOut[(o0 + l15) * 65 + px] = acc[pt][r];        // col=N=o
        }
    }
    __syncthreads();
    #pragma unroll
    for (int j = 0; j < 16; ++j) {
        const int o = wv * 16 + j;
        out[(((size_t)n * COUT + o) * HH + h) * WW + w0 + spx] = sOut[o * 65 + spx] + bias[o];
    }
}

extern "C" void kernel_launch(void* const* d_in, const int* in_sizes, int n_in,
                              void* d_out, int out_size, void* d_ws, size_t ws_size,
                              hipStream_t stream) {
    const float* x    = (const float*)d_in[0];
    const float* Kp   = (const float*)d_in[1];
    const float* wgt  = (const float*)d_in[2];
    const float* bias = (const float*)d_in[3];
    float* out = (float*)d_out;
    unsigned short* wB = (unsigned short*)d_ws;   // 64*640 bf16 = 81920 B

    prep_weight<<<(COUT * KTOT + 255) / 256, 256, 0, stream>>>(wgt, wB);

    pac_conv<<<NB * HH * (WW / PX), 256, 0, stream>>>(x, Kp, wB, bias, out);
}

// Round 3
// 30.655 us; speedup vs baseline: 2.3291x; 1.1020x over previous
//
#include <hip/hip_runtime.h>
#include <hip/hip_bf16.h>
#include <cstddef>

typedef __attribute__((ext_vector_type(8))) short bf16x8;
typedef __attribute__((ext_vector_type(4))) float f32x4;
typedef __attribute__((ext_vector_type(2))) unsigned int u32x2;

#define NB 4
#define CIN 64
#define COUT 64
#define HH 128
#define WW 128
#define TAPS 9
#define PX 64
#define KCH 160      // padded K per chunk (144 real + 16 zero)
#define KTOT 640
#define STRD 82      // sCor row stride in dwords (41 qwords: odd -> conflict-free b64)

__device__ __forceinline__ unsigned short f2bf(float f) {
    union { float f; unsigned u; } v; v.f = f;
    unsigned u = v.u + 0x7FFFu + ((v.u >> 16) & 1u);   // RNE
    return (unsigned short)(u >> 16);
}

// wB[o][kk], kk = chunk*160 + tap*16 + cl (zero-pad kl 144..159); also zero zrow[0..67]
__global__ void prep_weight(const float* __restrict__ w, unsigned short* __restrict__ wB,
                            float* __restrict__ zrow) {
    int idx = blockIdx.x * blockDim.x + threadIdx.x;
    if (idx < 68) zrow[idx] = 0.f;
    if (idx >= COUT * KTOT) return;
    int o = idx / KTOT;
    int kk = idx - o * KTOT;
    int chunk = kk / KCH;
    int kl = kk - chunk * KCH;
    unsigned short v = 0;
    if (kl < 16 * TAPS) {
        int tap = kl >> 4;
        int cl = kl & 15;
        v = f2bf(w[(o * CIN + chunk * 16 + cl) * TAPS + tap]);
    }
    wB[idx] = v;
}

__launch_bounds__(256, 4)
__global__ void pac_conv(const float* __restrict__ x, const float* __restrict__ Kp,
                         const unsigned short* __restrict__ wB,
                         const float* __restrict__ bias,
                         const float* __restrict__ zrow1,   // points at zrow+1 (covers idx -1..66)
                         float* __restrict__ out) {
    __shared__ unsigned int sCor[PX][STRD];   // 20992 B

    const int blk = blockIdx.x;               // 1024
    const int w0 = (blk & 1) * PX;
    const int h  = (blk >> 1) & (HH - 1);
    const int n  = blk >> 8;
    const int t    = threadIdx.x;
    const int lane = t & 63;
    const int wv   = __builtin_amdgcn_readfirstlane(t >> 6);

    // per-pixel adapting kernel straight to registers (lane = pixel)
    float kreg[TAPS];
    float ks = 0.f;
    const float* kp = Kp + ((size_t)n * TAPS * HH + h) * WW + w0 + lane;
    #pragma unroll
    for (int tap = 0; tap < TAPS; ++tap) {
        kreg[tap] = kp[(size_t)tap * HH * WW];
        ks += kreg[tap];
    }
    const float inv = 1.0f / ks;

    // zero the K-pad dwords (kl 144..159 -> dw 72..79)
    for (int i = t; i < PX * 8; i += 256) sCor[i >> 3][72 + (i & 7)] = 0u;

    // w-edge handling: base biased by -1 float; unsigned byte offsets
    const bool mL = (w0 == 0) && (lane == 0);
    const bool mR = (w0 != 0) && (lane == 63);
    const unsigned voffL = (mL ? 1u : (unsigned)lane) * 4u;        // tap l=0
    const unsigned voffC = ((unsigned)lane + 1u) * 4u;             // tap l=1
    const unsigned voffR = (mR ? 64u : (unsigned)lane + 2u) * 4u;  // tap l=2

    const int l15 = lane & 15;
    const int kg  = (lane >> 4) * 8;
    const float bval = bias[wv * 16 + l15];

    f32x4 acc[4];
    #pragma unroll
    for (int i = 0; i < 4; ++i) acc[i] = (f32x4){0.f, 0.f, 0.f, 0.f};

    for (int chunk = 0; chunk < 4; ++chunk) {
        const int c0 = chunk * 16 + wv * 4;               // wave-uniform
        const float* xb = x + (size_t)(n * CIN + c0) * (HH * WW) + w0 - 1;  // -1 bias

        // load 4 channels x 9 taps
        float xv[4][TAPS];
        #pragma unroll
        for (int k = 0; k < 3; ++k) {
            const int hh = h + k - 1;
            const bool hok = (unsigned)hh < (unsigned)HH;
            #pragma unroll
            for (int j = 0; j < 4; ++j) {
                const float* p = hok ? (xb + (size_t)j * (HH * WW) + hh * WW) : (zrow1 - 1);
                float vL = *(const float*)((const char*)p + voffL);
                float vC = *(const float*)((const char*)p + voffC);
                float vR = *(const float*)((const char*)p + voffR);
                xv[j][k * 3 + 0] = mL ? 0.f : vL;
                xv[j][k * 3 + 1] = vC;
                xv[j][k * 3 + 2] = mR ? 0.f : vR;
            }
        }

        // dominate + corrected, packed to bf16 pairs
        u32x2 cor[TAPS];
        float dom[4];
        #pragma unroll
        for (int j = 0; j < 4; ++j) {
            float s = 0.f;
            #pragma unroll
            for (int tap = 0; tap < TAPS; ++tap) s = fmaf(xv[j][tap], kreg[tap], s);
            dom[j] = s * inv;
        }
        #pragma unroll
        for (int tap = 0; tap < TAPS; ++tap) {
            float c01[4];
            #pragma unroll
            for (int j = 0; j < 4; ++j)
                c01[j] = fmaf(kreg[tap], xv[j][tap] - dom[j], dom[j]);
            union { __hip_bfloat162 h2; unsigned int u; } a, b;
            a.h2 = __float22bfloat162_rn(make_float2(c01[0], c01[1]));
            b.h2 = __float22bfloat162_rn(make_float2(c01[2], c01[3]));
            cor[tap] = (u32x2){a.u, b.u};
        }

        if (chunk) __syncthreads();           // previous MFMA readers done
        #pragma unroll
        for (int tap = 0; tap < TAPS; ++tap)
            *reinterpret_cast<u32x2*>(&sCor[lane][tap * 8 + wv * 2]) = cor[tap];
        __syncthreads();

        // MFMA: wave owns 16 outputs x 64 px
        const unsigned short* wrow = wB + (size_t)(wv * 16 + l15) * KTOT + chunk * KCH + kg;
        #pragma unroll
        for (int step = 0; step < 5; ++step) {
            bf16x8 bfrag = *reinterpret_cast<const bf16x8*>(wrow + step * 32);
            #pragma unroll
            for (int pt = 0; pt < 4; ++pt) {
                const unsigned int* ap = &sCor[pt * 16 + l15][(step * 32 + kg) >> 1];
                u32x2 alo = *reinterpret_cast<const u32x2*>(ap);
                u32x2 ahi = *reinterpret_cast<const u32x2*>(ap + 2);
                union { u32x2 p[2]; bf16x8 f; } af;
                af.p[0] = alo; af.p[1] = ahi;
                acc[pt] = __builtin_amdgcn_mfma_f32_16x16x32_bf16(af.f, bfrag, acc[pt], 0, 0, 0);
            }
        }
    }

    // epilogue: direct float4 stores (D rows = 4 consecutive px per thread)
    const int o = wv * 16 + l15;
    const int pxq = (lane >> 4) * 4;
    float* op = out + (((size_t)n * COUT + o) * HH + h) * WW + w0 + pxq;
    #pragma unroll
    for (int pt = 0; pt < 4; ++pt) {
        f32x4 v = acc[pt];
        #pragma unroll
        for (int r = 0; r < 4; ++r) v[r] += bval;
        *reinterpret_cast<f32x4*>(op + pt * 16) = v;
    }
}

extern "C" void kernel_launch(void* const* d_in, const int* in_sizes, int n_in,
                              void* d_out, int out_size, void* d_ws, size_t ws_size,
                              hipStream_t stream) {
    const float* x    = (const float*)d_in[0];
    const float* Kp   = (const float*)d_in[1];
    const float* wgt  = (const float*)d_in[2];
    const float* bias = (const float*)d_in[3];
    float* out = (float*)d_out;
    unsigned short* wB = (unsigned short*)d_ws;              // 81920 B
    float* zrow = (float*)((char*)d_ws + 81920);             // 68 floats

    prep_weight<<<(COUT * KTOT + 255) / 256, 256, 0, stream>>>(wgt, wB, zrow);

    pac_conv<<<NB * HH * (WW / PX), 256, 0, stream>>>(x, Kp, wB, bias, zrow + 1, out);
}